// Round 2
// baseline (668.505 us; speedup 1.0000x reference)
//
#include <hip/hip_runtime.h>

// ---------------- problem constants ----------------
#define NVEC  131072      // 32*4096 vectors
#define DIM   64
#define K     512
#define DECAYF 0.99f
#define OMDF   0.01f
#define EPSF   1e-5f
#define NBLK_ASSIGN (NVEC / 64)   // 2048 blocks, 64 vectors each

// ---------------- output layout (floats, concatenated in return order) ----
#define Q_OFF    0
#define DIFF_OFF 8388608
#define IND_OFF  8388609
#define NE_OFF   8519681
#define NCS_OFF  8552449
#define NEA_OFF  8552961

// ---------------- ws layout (floats) — ~1.2 MB ----
#define ET_OFF    0        // E^T : K x DIM
#define C_OFF     32768    // np-order sum(E*E, axis=0) : K
#define DPART_OFF 33280    // per-assign-block diff partials : 2048
#define INDI_OFF  35328    // int copy of indices : NVEC
#define PCNT_OFF  166400   // count partials : 4 x K
#define PESUM_OFF 168448   // esum partials : 4 x K x DIM
#define NSH_OFF   299520   // scalar n (1 float) for split finalize
// end: 299521 floats = 1.17 MB (known-safe: r4 used 1.33 MB)

// ============ prep: transpose embed -> E^T, C_j = np.sum(E*E, axis=0) ====
__global__ __launch_bounds__(256) void vq_prep(const float* __restrict__ embed,
                                               float* __restrict__ ws) {
    #pragma clang fp contract(off)
    int j = blockIdx.x * 256 + threadIdx.x;
    float c = 0.0f;
    for (int d = 0; d < DIM; ++d) {
        float v = embed[d * K + j];           // coalesced across j
        ws[ET_OFF + j * DIM + d] = v;
        float t = v * v;
        c = c + t;
    }
    ws[C_OFF + j] = c;
}

// ============ main: np-fp32-replica argmin, 4-way K-split ================
// r1 post-mortem: SMEM e-stream can't be double-buffered (64 e-floats ≈
// the whole SGPR budget) -> every unroll-4 group pays an exposed lgkm
// wait (~300 cyc per 512-cyc FMA group). THIS ROUND: e-loads become
// wave-uniform VMEM loads into VGPRs (opaque lane-zero in the address so
// the compiler can't re-scalarize). Same bytes/broadcast, but vmcnt
// pipelining runs loads arbitrarily deep across unroll groups. Per-element
// fp32 math and ordering are bit-identical to the passing kernel.
// waves_per_eu min=3 -> VGPR budget ~170 (f[64] + e-window + working),
// no spill expected.
__global__ __launch_bounds__(256)
__attribute__((amdgpu_waves_per_eu(3, 8)))
void vq_assign(
    const float* __restrict__ x,
    const float* __restrict__ ET,      // ws + ET_OFF
    const float* __restrict__ C,       // ws + C_OFF
    int*   __restrict__ indI,          // ws + INDI_OFF
    float* __restrict__ dpart,         // ws + DPART_OFF
    float* __restrict__ out)
{
    #pragma clang fp contract(off)
    __shared__ float sd[4][64];
    __shared__ int   si[4][64];
    __shared__ int   sbest[64];
    __shared__ float wdl[4];

    int lane = threadIdx.x & 63;
    int wq   = __builtin_amdgcn_readfirstlane(threadIdx.x >> 6); // wave-uniform
    int v    = blockIdx.x * 64 + lane;
    const float* fx = x + (size_t)v * DIM;

    float f[DIM];
    #pragma unroll
    for (int k = 0; k < DIM / 4; ++k) {
        float4 t = ((const float4*)fx)[k];
        f[4*k+0] = t.x; f[4*k+1] = t.y; f[4*k+2] = t.z; f[4*k+3] = t.w;
    }

    // Pin f[0..63] in VGPRs. Identity on values (no clobbers).
    #define PIN16(b) asm volatile("" \
        : "+v"(f[(b)+0]),  "+v"(f[(b)+1]),  "+v"(f[(b)+2]),  "+v"(f[(b)+3]), \
          "+v"(f[(b)+4]),  "+v"(f[(b)+5]),  "+v"(f[(b)+6]),  "+v"(f[(b)+7]), \
          "+v"(f[(b)+8]),  "+v"(f[(b)+9]),  "+v"(f[(b)+10]), "+v"(f[(b)+11]), \
          "+v"(f[(b)+12]), "+v"(f[(b)+13]), "+v"(f[(b)+14]), "+v"(f[(b)+15]))
    PIN16(0); PIN16(16); PIN16(32); PIN16(48);
    #undef PIN16

    // A = np.sum(f*f, axis=1): numpy pairwise, n=64 -> 8 accumulators over
    // strides of 8, then ((r0+r1)+(r2+r3))+((r4+r5)+(r6+r7)). Plain mul+add.
    float r[8];
    #pragma unroll
    for (int k = 0; k < 8; ++k) r[k] = f[k] * f[k];
    #pragma unroll
    for (int b = 1; b < 8; ++b) {
        #pragma unroll
        for (int k = 0; k < 8; ++k) {
            float t = f[8*b + k] * f[8*b + k];
            r[k] = r[k] + t;
        }
    }
    float A = ((r[0] + r[1]) + (r[2] + r[3])) + ((r[4] + r[5]) + (r[6] + r[7]));

    // Opaque per-lane zero: forces the e-loads onto the VMEM path (VGPR
    // destination, vmcnt pipelining) instead of SMEM/SGPR. Value is 0, so
    // addresses and loaded bytes are identical to the scalar version.
    int zoff = 0;
    asm volatile("" : "+v"(zoff));

    // scan this wave's 128 codes. Per-j fp32 sequence bit-identical to the
    // round-2 passing kernel (d ascending, single fma chain).
    const float* eseg = ET + (size_t)wq * 128 * DIM + zoff;
    const float* Cseg = C + wq * 128;          // tiny: stays scalar
    float bestd = 3.0e38f;
    int   besti = wq * 128;
    #pragma unroll 4
    for (int jj = 0; jj < 128; ++jj) {
        const float4* e4 = (const float4*)(eseg + jj * DIM);
        float m = 0.0f;
        #pragma unroll
        for (int k = 0; k < 16; ++k) {
            float4 ev = e4[k];
            m = __builtin_fmaf(f[4*k+0], ev.x, m);
            m = __builtin_fmaf(f[4*k+1], ev.y, m);
            m = __builtin_fmaf(f[4*k+2], ev.z, m);
            m = __builtin_fmaf(f[4*k+3], ev.w, m);
        }
        float t1 = 2.0f * m;             // exact (x2)
        float t2 = A - t1;               // rounded at ulp(~64)
        float dist = t2 + Cseg[jj];      // rounded
        if (dist < bestd) { bestd = dist; besti = wq * 128 + jj; }
    }

    sd[wq][lane] = bestd;
    si[wq][lane] = besti;
    __syncthreads();

    if (wq == 0) {
        float bd = sd[0][lane];
        int   bi = si[0][lane];
        #pragma unroll
        for (int q = 1; q < 4; ++q) {
            float d2 = sd[q][lane];
            int   i2 = si[q][lane];
            if (d2 < bd || (d2 == bd && i2 < bi)) { bd = d2; bi = i2; }
        }
        sbest[lane] = bi;
        out[IND_OFF + v] = (float)bi;    // coalesced
        indI[v] = bi;                    // int copy for vq_stats
    }
    __syncthreads();

    // epilogue: wave w handles a 16-float quarter of each row.
    // STATIC indexing only — x quarter reloaded from global (L1-hot).
    int bi = sbest[lane];
    const float* qrow = ET + (size_t)bi * DIM + wq * 16;
    const float* xrow = fx + wq * 16;
    float* orow = out + Q_OFF + (size_t)v * DIM + wq * 16;
    float dl = 0.0f;
    #pragma unroll
    for (int k = 0; k < 4; ++k) {
        float4 tq = ((const float4*)qrow)[k];
        float4 tx = ((const float4*)xrow)[k];
        float r0 = tq.x - tx.x;
        float r1 = tq.y - tx.y;
        float r2 = tq.z - tx.z;
        float r3 = tq.w - tx.w;
        dl = __builtin_fmaf(r0, r0, dl); dl = __builtin_fmaf(r1, r1, dl);
        dl = __builtin_fmaf(r2, r2, dl); dl = __builtin_fmaf(r3, r3, dl);
        ((float4*)orow)[k] = tq;
    }

    #pragma unroll
    for (int off = 32; off > 0; off >>= 1) dl += __shfl_down(dl, off);
    if (lane == 0) wdl[wq] = dl;
    __syncthreads();
    if (threadIdx.x == 0)
        dpart[blockIdx.x] = ((wdl[0] + wdl[1]) + (wdl[2] + wdl[3]));
}

// ============ stats: 4 blocks x 8 waves per code, int4 ballot scan =======
__global__ __launch_bounds__(512) void vq_stats(
    const float* __restrict__ x,
    const int* __restrict__ indI,      // ws + INDI_OFF
    float* __restrict__ pcnt,          // ws + PCNT_OFF   [4][K]
    float* __restrict__ pesum)         // ws + PESUM_OFF  [4][K][DIM]
{
    __shared__ float p[8][DIM];
    __shared__ float c[8];
    int j    = blockIdx.x >> 2;
    int q    = blockIdx.x & 3;
    int lane = threadIdx.x & 63;
    int w    = __builtin_amdgcn_readfirstlane(threadIdx.x >> 6);

    int seg  = q * 8 + w;              // 0..31
    int base = seg * (NVEC / 32);      // 4096 ids per segment

    float acc = 0.0f;
    int   cnt = 0;
    for (int i = 0; i < NVEC / 32; i += 256) {
        int4 idv = ((const int4*)(indI + base + i))[lane];  // 256 ids/wave
        unsigned long long m0 = __ballot(idv.x == j);
        unsigned long long m1 = __ballot(idv.y == j);
        unsigned long long m2 = __ballot(idv.z == j);
        unsigned long long m3 = __ballot(idv.w == j);
        cnt += (int)(__popcll(m0) + __popcll(m1) + __popcll(m2) + __popcll(m3));
        while (m0) { int b = __builtin_ctzll(m0); m0 &= m0 - 1;
                     acc += x[(size_t)(base + i + 4*b + 0) * DIM + lane]; }
        while (m1) { int b = __builtin_ctzll(m1); m1 &= m1 - 1;
                     acc += x[(size_t)(base + i + 4*b + 1) * DIM + lane]; }
        while (m2) { int b = __builtin_ctzll(m2); m2 &= m2 - 1;
                     acc += x[(size_t)(base + i + 4*b + 2) * DIM + lane]; }
        while (m3) { int b = __builtin_ctzll(m3); m3 &= m3 - 1;
                     acc += x[(size_t)(base + i + 4*b + 3) * DIM + lane]; }
    }
    p[w][lane] = acc;
    if (lane == 0) c[w] = (float)cnt;
    __syncthreads();
    if (w == 0) {
        float s = ((p[0][lane] + p[1][lane]) + (p[2][lane] + p[3][lane]))
                + ((p[4][lane] + p[5][lane]) + (p[6][lane] + p[7][lane]));
        pesum[((size_t)q * K + j) * DIM + lane] = s;
        if (lane == 0)
            pcnt[q * K + j] = ((c[0] + c[1]) + (c[2] + c[3]))
                            + ((c[4] + c[5]) + (c[6] + c[7]));
    }
}

// ============ finalize stage 1: scalars (ncs, n, diff) — 1 block =========
__global__ __launch_bounds__(512) void vq_finalize1(
    const float* __restrict__ cluster_size,
    float* __restrict__ ws,
    float* __restrict__ out)
{
    __shared__ float wsum[8];
    __shared__ float dsum_sh[8];
    int j = threadIdx.x;  // 512 threads, one per code

    float cj = ((ws[PCNT_OFF + 0*K + j] + ws[PCNT_OFF + 1*K + j])
              + (ws[PCNT_OFF + 2*K + j] + ws[PCNT_OFF + 3*K + j]));
    float ncs = DECAYF * cluster_size[j] + OMDF * cj;
    out[NCS_OFF + j] = ncs;

    // diff: sum 2048 block partials (deterministic)
    float dsum = 0.0f;
    #pragma unroll
    for (int k = 0; k < NBLK_ASSIGN / 512; ++k)
        dsum += ws[DPART_OFF + k * 512 + j];

    float s = ncs;
    #pragma unroll
    for (int off = 32; off > 0; off >>= 1) {
        s    += __shfl_down(s, off);
        dsum += __shfl_down(dsum, off);
    }
    if ((j & 63) == 0) { wsum[j >> 6] = s; dsum_sh[j >> 6] = dsum; }
    __syncthreads();
    if (j == 0) {
        float n = 0.f, dtot = 0.f;
        #pragma unroll
        for (int w = 0; w < 8; ++w) { n += wsum[w]; dtot += dsum_sh[w]; }
        ws[NSH_OFF] = n;
        out[DIFF_OFF] = dtot * (1.0f / 8388608.0f);  // 2^23: exact
    }
}

// ============ finalize stage 2: embed EMA + normalize — 64 blocks ========
// Pure parallelization of the old single-block d-loop: block = one d,
// thread = one j. Element math identical (same sum order, same csz ops on
// identical ncs/n floats) -> bit-identical outputs.
__global__ __launch_bounds__(512) void vq_finalize2(
    const float* __restrict__ embed_avg,
    const float* __restrict__ ws,
    float* __restrict__ out)
{
    int d = blockIdx.x;     // 0..63
    int j = threadIdx.x;    // 0..511

    float ncs = out[NCS_OFF + j];
    float n   = ws[NSH_OFF];
    float csz = (ncs + EPSF) / (n + (float)K * EPSF) * n;

    float es = ((ws[PESUM_OFF + ((size_t)0*K + j) * DIM + d]
               + ws[PESUM_OFF + ((size_t)1*K + j) * DIM + d])
              + (ws[PESUM_OFF + ((size_t)2*K + j) * DIM + d]
               + ws[PESUM_OFF + ((size_t)3*K + j) * DIM + d]));
    float ea = DECAYF * embed_avg[d * K + j] + OMDF * es;
    out[NEA_OFF + d * K + j] = ea;        // coalesced over j
    out[NE_OFF  + d * K + j] = ea / csz;
}

// ============ launch ============
extern "C" void kernel_launch(void* const* d_in, const int* in_sizes, int n_in,
                              void* d_out, int out_size, void* d_ws, size_t ws_size,
                              hipStream_t stream) {
    const float* x            = (const float*)d_in[0];
    const float* embed        = (const float*)d_in[1];
    const float* cluster_size = (const float*)d_in[2];
    const float* embed_avg    = (const float*)d_in[3];
    float* out = (float*)d_out;
    float* ws  = (float*)d_ws;
    int*   indI = (int*)(ws + INDI_OFF);

    vq_prep<<<K / 256, 256, 0, stream>>>(embed, ws);
    vq_assign<<<NBLK_ASSIGN, 256, 0, stream>>>(
        x, ws + ET_OFF, ws + C_OFF, indI, ws + DPART_OFF, out);
    vq_stats<<<K * 4, 512, 0, stream>>>(
        x, indI, ws + PCNT_OFF, ws + PESUM_OFF);
    vq_finalize1<<<1, K, 0, stream>>>(cluster_size, ws, out);
    vq_finalize2<<<DIM, K, 0, stream>>>(embed_avg, ws, out);
}

// Round 3
// 350.228 us; speedup vs baseline: 1.9088x; 1.9088x over previous
//
#include <hip/hip_runtime.h>

// ---------------- problem constants ----------------
#define NVEC  131072      // 32*4096 vectors
#define DIM   64
#define K     512
#define DECAYF 0.99f
#define OMDF   0.01f
#define EPSF   1e-5f
#define VPB   128                 // vectors per block: 64 lanes x 2 vectors
#define NBLK_ASSIGN (NVEC / VPB)  // 1024 blocks, 1 wave each
#define NCHUNK 16                 // 16 code chunks of 32
#define CHUNK  32

// ---------------- output layout (floats, concatenated in return order) ----
#define Q_OFF    0
#define DIFF_OFF 8388608
#define IND_OFF  8388609
#define NE_OFF   8519681
#define NCS_OFF  8552449
#define NEA_OFF  8552961

// ---------------- ws layout (floats) — ~1.2 MB ----
#define ET_OFF    0        // E^T : K x DIM
#define C_OFF     32768    // np-order sum(E*E, axis=0) : K
#define DPART_OFF 33280    // per-assign-block diff partials : 1024 (region holds 2048)
#define INDI_OFF  35328    // int copy of indices : NVEC
#define PCNT_OFF  166400   // count partials : 4 x K
#define PESUM_OFF 168448   // esum partials : 4 x K x DIM
#define NSH_OFF   299520   // scalar n (1 float) for split finalize
// end: 299521 floats = 1.17 MB (known-safe: r4 used 1.33 MB)

// ============ prep: transpose embed -> E^T, C_j = np.sum(E*E, axis=0) ====
__global__ __launch_bounds__(256) void vq_prep(const float* __restrict__ embed,
                                               float* __restrict__ ws) {
    #pragma clang fp contract(off)
    int j = blockIdx.x * 256 + threadIdx.x;
    float c = 0.0f;
    for (int d = 0; d < DIM; ++d) {
        float v = embed[d * K + j];           // coalesced across j
        ws[ET_OFF + j * DIM + d] = v;
        float t = v * v;
        c = c + t;
    }
    ws[C_OFF + j] = c;
}

// ============ main: np-fp32-replica argmin, LDS-broadcast e-stream =======
// Round-2 lesson: per-lane VMEM e-loads expose L1 latency (592 µs). Round-1
// lesson: SMEM e-stream inflates VALU ~2x (v_mov SGPR->VGPR copies; 160 µs).
// THIS ROUND: e is staged per 32-code chunk into LDS (double-buffered,
// 16 KB) by coalesced float4 loads, then consumed via uniform-address
// ds_read_b128 (broadcast: conflict-free, lands directly in VGPRs, deep
// lgkm pipelining). Each e-read feeds TWO vectors per lane (fa, fb pinned:
// 128 VGPRs) -> 2 independent FMA chains give full VALU issue rate from a
// single wave, so blocks are 1 wave (no barriers at all; within-wave DS
// ordering via lgkmcnt). Staging loads for chunk c+1 issue before the
// chunk-c compute and the ds_writes land after it (latency hidden).
// Per-(v,j) fp32 distance sequence is bit-identical to the passing kernel:
// d-ascending single fmaf chain, t1=2m (exact), t2=A-t1, dist=t2+C[j];
// A = exact 8-accumulator pairwise; argmin = j-ascending strict '<'
// (first-min == numpy; == previous segment-scan + index tie-break).
__global__ __launch_bounds__(64)
__attribute__((amdgpu_waves_per_eu(1, 8)))
void vq_assign(
    const float* __restrict__ x,
    const float* __restrict__ ET,      // ws + ET_OFF
    const float* __restrict__ C,       // ws + C_OFF
    int*   __restrict__ indI,          // ws + INDI_OFF
    float* __restrict__ dpart,         // ws + DPART_OFF
    float* __restrict__ out)
{
    #pragma clang fp contract(off)
    __shared__ float ebuf[2][CHUNK][DIM];   // 16 KB double-buffered code chunk

    int tid = threadIdx.x;                  // 0..63, single wave
    int va  = blockIdx.x * VPB + tid;
    int vb  = va + 64;
    const float* fxa = x + (size_t)va * DIM;
    const float* fxb = x + (size_t)vb * DIM;

    float fa[DIM], fb[DIM];
    #pragma unroll
    for (int k = 0; k < DIM / 4; ++k) {
        float4 t = ((const float4*)fxa)[k];
        fa[4*k+0] = t.x; fa[4*k+1] = t.y; fa[4*k+2] = t.z; fa[4*k+3] = t.w;
    }
    #pragma unroll
    for (int k = 0; k < DIM / 4; ++k) {
        float4 t = ((const float4*)fxb)[k];
        fb[4*k+0] = t.x; fb[4*k+1] = t.y; fb[4*k+2] = t.z; fb[4*k+3] = t.w;
    }

    // Pin fa/fb in VGPRs (identity asm; values defined by asm can't be
    // rematerialized from memory). 128 VGPRs pinned; waves_per_eu(1,8)
    // relaxes the allocator so the ~210-reg working set never spills
    // (occupancy is 1 wave/SIMD by grid anyway: 1024 waves / 1024 SIMDs).
    #define PIN16(a, b) asm volatile("" \
        : "+v"(a[(b)+0]),  "+v"(a[(b)+1]),  "+v"(a[(b)+2]),  "+v"(a[(b)+3]), \
          "+v"(a[(b)+4]),  "+v"(a[(b)+5]),  "+v"(a[(b)+6]),  "+v"(a[(b)+7]), \
          "+v"(a[(b)+8]),  "+v"(a[(b)+9]),  "+v"(a[(b)+10]), "+v"(a[(b)+11]), \
          "+v"(a[(b)+12]), "+v"(a[(b)+13]), "+v"(a[(b)+14]), "+v"(a[(b)+15]))
    PIN16(fa, 0); PIN16(fa, 16); PIN16(fa, 32); PIN16(fa, 48);
    PIN16(fb, 0); PIN16(fb, 16); PIN16(fb, 32); PIN16(fb, 48);
    #undef PIN16

    // A per vector: numpy pairwise, n=64 -> 8 accumulators stride 8, then
    // ((r0+r1)+(r2+r3))+((r4+r5)+(r6+r7)). Plain mul+add (contract off).
    float ra[8], rb[8];
    #pragma unroll
    for (int k = 0; k < 8; ++k) { ra[k] = fa[k] * fa[k]; rb[k] = fb[k] * fb[k]; }
    #pragma unroll
    for (int b = 1; b < 8; ++b) {
        #pragma unroll
        for (int k = 0; k < 8; ++k) {
            float t0 = fa[8*b + k] * fa[8*b + k];
            ra[k] = ra[k] + t0;
            float t1 = fb[8*b + k] * fb[8*b + k];
            rb[k] = rb[k] + t1;
        }
    }
    float Aa = ((ra[0] + ra[1]) + (ra[2] + ra[3])) + ((ra[4] + ra[5]) + (ra[6] + ra[7]));
    float Ab = ((rb[0] + rb[1]) + (rb[2] + rb[3])) + ((rb[4] + rb[5]) + (rb[6] + rb[7]));

    // stage chunk 0 (codes 0..31): 2048 floats, 8 coalesced float4/lane
    const float4* ET4 = (const float4*)ET;
    {
        float4* wb0 = (float4*)&ebuf[0][0][0];
        #pragma unroll
        for (int r = 0; r < 8; ++r)
            wb0[r*64 + tid] = ET4[r*64 + tid];
    }

    float bda = 3.0e38f, bdb = 3.0e38f;
    int   bia = 0,       bib = 0;

    for (int c = 0; c < NCHUNK; ++c) {
        const float* eb = &ebuf[c & 1][0][0];
        // issue next-chunk staging loads BEFORE compute (latency hidden)
        float4 st[8];
        if (c < NCHUNK - 1) {
            #pragma unroll
            for (int r = 0; r < 8; ++r)
                st[r] = ET4[(c + 1) * 512 + r*64 + tid];
        }
        #pragma unroll 4
        for (int jj = 0; jj < CHUNK; ++jj) {
            const float4* e4 = (const float4*)(eb + jj * DIM);
            float ma = 0.0f, mb = 0.0f;
            #pragma unroll
            for (int k = 0; k < 16; ++k) {
                float4 ev = e4[k];          // broadcast ds_read_b128
                ma = __builtin_fmaf(fa[4*k+0], ev.x, ma);
                ma = __builtin_fmaf(fa[4*k+1], ev.y, ma);
                ma = __builtin_fmaf(fa[4*k+2], ev.z, ma);
                ma = __builtin_fmaf(fa[4*k+3], ev.w, ma);
                mb = __builtin_fmaf(fb[4*k+0], ev.x, mb);
                mb = __builtin_fmaf(fb[4*k+1], ev.y, mb);
                mb = __builtin_fmaf(fb[4*k+2], ev.z, mb);
                mb = __builtin_fmaf(fb[4*k+3], ev.w, mb);
            }
            int j = c * CHUNK + jj;
            float Cv = C[j];                 // uniform -> scalar load
            float t1a = 2.0f * ma;           // exact (x2)
            float t2a = Aa - t1a;            // rounded
            float da  = t2a + Cv;            // rounded
            float t1b = 2.0f * mb;
            float t2b = Ab - t1b;
            float db  = t2b + Cv;
            if (da < bda) { bda = da; bia = j; }
            if (db < bdb) { bdb = db; bib = j; }
        }
        // write next chunk AFTER compute; reads of that buffer finished in
        // chunk c-1 (same wave, DS in-order). No barrier: single-wave block.
        if (c < NCHUNK - 1) {
            float4* wb = (float4*)&ebuf[(c + 1) & 1][0][0];
            #pragma unroll
            for (int r = 0; r < 8; ++r)
                wb[r*64 + tid] = st[r];
        }
    }

    // ---------------- epilogue: ind, quantize copy, diff partial ---------
    out[IND_OFF + va] = (float)bia;          // 4B stores, coalesced over tid
    out[IND_OFF + vb] = (float)bib;
    indI[va] = bia;
    indI[vb] = bib;

    const float4* qa = (const float4*)(ET + (size_t)bia * DIM);
    const float4* qb = (const float4*)(ET + (size_t)bib * DIM);
    float4* oa = (float4*)(out + Q_OFF + (size_t)va * DIM);
    float4* ob = (float4*)(out + Q_OFF + (size_t)vb * DIM);
    float dl = 0.0f;
    #pragma unroll
    for (int k = 0; k < 16; ++k) {
        float4 tq = qa[k];
        float r0 = tq.x - fa[4*k+0];
        float r1 = tq.y - fa[4*k+1];
        float r2 = tq.z - fa[4*k+2];
        float r3 = tq.w - fa[4*k+3];
        dl = __builtin_fmaf(r0, r0, dl); dl = __builtin_fmaf(r1, r1, dl);
        dl = __builtin_fmaf(r2, r2, dl); dl = __builtin_fmaf(r3, r3, dl);
        oa[k] = tq;
    }
    #pragma unroll
    for (int k = 0; k < 16; ++k) {
        float4 tq = qb[k];
        float r0 = tq.x - fb[4*k+0];
        float r1 = tq.y - fb[4*k+1];
        float r2 = tq.z - fb[4*k+2];
        float r3 = tq.w - fb[4*k+3];
        dl = __builtin_fmaf(r0, r0, dl); dl = __builtin_fmaf(r1, r1, dl);
        dl = __builtin_fmaf(r2, r2, dl); dl = __builtin_fmaf(r3, r3, dl);
        ob[k] = tq;
    }

    #pragma unroll
    for (int off = 32; off > 0; off >>= 1) dl += __shfl_down(dl, off);
    if (tid == 0) dpart[blockIdx.x] = dl;
}

// ============ stats: 4 blocks x 8 waves per code, int4 ballot scan =======
__global__ __launch_bounds__(512) void vq_stats(
    const float* __restrict__ x,
    const int* __restrict__ indI,      // ws + INDI_OFF
    float* __restrict__ pcnt,          // ws + PCNT_OFF   [4][K]
    float* __restrict__ pesum)         // ws + PESUM_OFF  [4][K][DIM]
{
    __shared__ float p[8][DIM];
    __shared__ float c[8];
    int j    = blockIdx.x >> 2;
    int q    = blockIdx.x & 3;
    int lane = threadIdx.x & 63;
    int w    = __builtin_amdgcn_readfirstlane(threadIdx.x >> 6);

    int seg  = q * 8 + w;              // 0..31
    int base = seg * (NVEC / 32);      // 4096 ids per segment

    float acc = 0.0f;
    int   cnt = 0;
    for (int i = 0; i < NVEC / 32; i += 256) {
        int4 idv = ((const int4*)(indI + base + i))[lane];  // 256 ids/wave
        unsigned long long m0 = __ballot(idv.x == j);
        unsigned long long m1 = __ballot(idv.y == j);
        unsigned long long m2 = __ballot(idv.z == j);
        unsigned long long m3 = __ballot(idv.w == j);
        cnt += (int)(__popcll(m0) + __popcll(m1) + __popcll(m2) + __popcll(m3));
        while (m0) { int b = __builtin_ctzll(m0); m0 &= m0 - 1;
                     acc += x[(size_t)(base + i + 4*b + 0) * DIM + lane]; }
        while (m1) { int b = __builtin_ctzll(m1); m1 &= m1 - 1;
                     acc += x[(size_t)(base + i + 4*b + 1) * DIM + lane]; }
        while (m2) { int b = __builtin_ctzll(m2); m2 &= m2 - 1;
                     acc += x[(size_t)(base + i + 4*b + 2) * DIM + lane]; }
        while (m3) { int b = __builtin_ctzll(m3); m3 &= m3 - 1;
                     acc += x[(size_t)(base + i + 4*b + 3) * DIM + lane]; }
    }
    p[w][lane] = acc;
    if (lane == 0) c[w] = (float)cnt;
    __syncthreads();
    if (w == 0) {
        float s = ((p[0][lane] + p[1][lane]) + (p[2][lane] + p[3][lane]))
                + ((p[4][lane] + p[5][lane]) + (p[6][lane] + p[7][lane]));
        pesum[((size_t)q * K + j) * DIM + lane] = s;
        if (lane == 0)
            pcnt[q * K + j] = ((c[0] + c[1]) + (c[2] + c[3]))
                            + ((c[4] + c[5]) + (c[6] + c[7]));
    }
}

// ============ finalize stage 1: scalars (ncs, n, diff) — 1 block =========
__global__ __launch_bounds__(512) void vq_finalize1(
    const float* __restrict__ cluster_size,
    float* __restrict__ ws,
    float* __restrict__ out)
{
    __shared__ float wsum[8];
    __shared__ float dsum_sh[8];
    int j = threadIdx.x;  // 512 threads, one per code

    float cj = ((ws[PCNT_OFF + 0*K + j] + ws[PCNT_OFF + 1*K + j])
              + (ws[PCNT_OFF + 2*K + j] + ws[PCNT_OFF + 3*K + j]));
    float ncs = DECAYF * cluster_size[j] + OMDF * cj;
    out[NCS_OFF + j] = ncs;

    // diff: sum 1024 block partials (deterministic)
    float dsum = 0.0f;
    #pragma unroll
    for (int k = 0; k < NBLK_ASSIGN / 512; ++k)
        dsum += ws[DPART_OFF + k * 512 + j];

    float s = ncs;
    #pragma unroll
    for (int off = 32; off > 0; off >>= 1) {
        s    += __shfl_down(s, off);
        dsum += __shfl_down(dsum, off);
    }
    if ((j & 63) == 0) { wsum[j >> 6] = s; dsum_sh[j >> 6] = dsum; }
    __syncthreads();
    if (j == 0) {
        float n = 0.f, dtot = 0.f;
        #pragma unroll
        for (int w = 0; w < 8; ++w) { n += wsum[w]; dtot += dsum_sh[w]; }
        ws[NSH_OFF] = n;
        out[DIFF_OFF] = dtot * (1.0f / 8388608.0f);  // 2^23: exact
    }
}

// ============ finalize stage 2: embed EMA + normalize — 64 blocks ========
__global__ __launch_bounds__(512) void vq_finalize2(
    const float* __restrict__ embed_avg,
    const float* __restrict__ ws,
    float* __restrict__ out)
{
    int d = blockIdx.x;     // 0..63
    int j = threadIdx.x;    // 0..511

    float ncs = out[NCS_OFF + j];
    float n   = ws[NSH_OFF];
    float csz = (ncs + EPSF) / (n + (float)K * EPSF) * n;

    float es = ((ws[PESUM_OFF + ((size_t)0*K + j) * DIM + d]
               + ws[PESUM_OFF + ((size_t)1*K + j) * DIM + d])
              + (ws[PESUM_OFF + ((size_t)2*K + j) * DIM + d]
               + ws[PESUM_OFF + ((size_t)3*K + j) * DIM + d]));
    float ea = DECAYF * embed_avg[d * K + j] + OMDF * es;
    out[NEA_OFF + d * K + j] = ea;        // coalesced over j
    out[NE_OFF  + d * K + j] = ea / csz;
}

// ============ launch ============
extern "C" void kernel_launch(void* const* d_in, const int* in_sizes, int n_in,
                              void* d_out, int out_size, void* d_ws, size_t ws_size,
                              hipStream_t stream) {
    const float* x            = (const float*)d_in[0];
    const float* embed        = (const float*)d_in[1];
    const float* cluster_size = (const float*)d_in[2];
    const float* embed_avg    = (const float*)d_in[3];
    float* out = (float*)d_out;
    float* ws  = (float*)d_ws;
    int*   indI = (int*)(ws + INDI_OFF);

    vq_prep<<<K / 256, 256, 0, stream>>>(embed, ws);
    vq_assign<<<NBLK_ASSIGN, 64, 0, stream>>>(
        x, ws + ET_OFF, ws + C_OFF, indI, ws + DPART_OFF, out);
    vq_stats<<<K * 4, 512, 0, stream>>>(
        x, indI, ws + PCNT_OFF, ws + PESUM_OFF);
    vq_finalize1<<<1, K, 0, stream>>>(cluster_size, ws, out);
    vq_finalize2<<<DIM, K, 0, stream>>>(embed_avg, ws, out);
}

// Round 4
// 339.866 us; speedup vs baseline: 1.9670x; 1.0305x over previous
//
#include <hip/hip_runtime.h>

// ---------------- problem constants ----------------
#define NVEC  131072      // 32*4096 vectors
#define DIM   64
#define K     512
#define DECAYF 0.99f
#define OMDF   0.01f
#define EPSF   1e-5f
#define VPB   128                 // vectors per block: 64 lanes x 2 vectors
#define NBLK_ASSIGN (NVEC / VPB)  // 1024 blocks, 2 waves each

// ---------------- output layout (floats, concatenated in return order) ----
#define Q_OFF    0
#define DIFF_OFF 8388608
#define IND_OFF  8388609
#define NE_OFF   8519681
#define NCS_OFF  8552449
#define NEA_OFF  8552961

// ---------------- ws layout (floats) — ~1.2 MB ----
#define ET_OFF    0        // E^T : K x DIM
#define C_OFF     32768    // np-order sum(E*E, axis=0) : K
#define DPART_OFF 33280    // per-assign-block diff partials : 1024
#define INDI_OFF  35328    // int copy of indices : NVEC
#define PCNT_OFF  166400   // count partials : 4 x K
#define PESUM_OFF 168448   // esum partials : 4 x K x DIM
#define NSH_OFF   299520   // scalar n (1 float) for split finalize
// end: 299521 floats = 1.17 MB (known-safe: r4 used 1.33 MB)

// ============ prep: transpose embed -> E^T, C_j = np.sum(E*E, axis=0) ====
__global__ __launch_bounds__(256) void vq_prep(const float* __restrict__ embed,
                                               float* __restrict__ ws) {
    #pragma clang fp contract(off)
    int j = blockIdx.x * 256 + threadIdx.x;
    float c = 0.0f;
    for (int d = 0; d < DIM; ++d) {
        float v = embed[d * K + j];           // coalesced across j
        ws[ET_OFF + j * DIM + d] = v;
        float t = v * v;
        c = c + t;
    }
    ws[C_OFF + j] = c;
}

// ============ main: np-fp32-replica argmin, SMEM e-stream, R=2 ==========
// Design-space map from rounds 1-3:
//   R1 SMEM stream, R=1:   160 µs (best; stalls on lgkm, 1 e-float/FMA)
//   R2 per-lane VMEM:      592 µs (latency death)
//   R3 LDS broadcast, R=2: 254 µs (DS pipe 3x oversubscribed: broadcast
//                                  ds_read_b128 still costs ~12 cyc)
// THIS ROUND: R1's scalar e-stream + R3's R=2 residency. Each s_loaded
// e-float feeds TWO independent FMA chains (fa,fb pinned: 128 VGPRs) ->
// stream pressure per FMA halves and the dual chains fill issue slots
// during SMEM waits. Block = 128 thr = 2 waves; wave wq scans codes
// [wq*256, wq*256+256) for all 128 vectors; 2-way merge = proven R0/R1
// logic (tie -> smaller index = numpy first-min). 2048 waves = 8/CU.
// Per-(v,j) fp32 sequence bit-identical to the passing kernels:
// d-ascending single fmaf chain per vector, t1=2m (exact), t2=A-t1,
// dist=t2+C[j]; A = exact 8-accumulator pairwise; strict '<' ascending j.
__global__ __launch_bounds__(128)
__attribute__((amdgpu_waves_per_eu(2, 8)))
void vq_assign(
    const float* __restrict__ x,
    const float* __restrict__ ET,      // ws + ET_OFF
    const float* __restrict__ C,       // ws + C_OFF
    int*   __restrict__ indI,          // ws + INDI_OFF
    float* __restrict__ dpart,         // ws + DPART_OFF
    float* __restrict__ out)
{
    #pragma clang fp contract(off)
    __shared__ float sda[2][64], sdb[2][64];
    __shared__ int   sia[2][64], sib[2][64];
    __shared__ int   sba[64], sbb[64];
    __shared__ float wdl[2];

    int lane = threadIdx.x & 63;
    int wq   = __builtin_amdgcn_readfirstlane(threadIdx.x >> 6); // 0 or 1
    int va   = blockIdx.x * VPB + lane;
    int vb   = va + 64;
    const float* fxa = x + (size_t)va * DIM;
    const float* fxb = x + (size_t)vb * DIM;

    float fa[DIM], fb[DIM];
    #pragma unroll
    for (int k = 0; k < DIM / 4; ++k) {
        float4 t = ((const float4*)fxa)[k];
        fa[4*k+0] = t.x; fa[4*k+1] = t.y; fa[4*k+2] = t.z; fa[4*k+3] = t.w;
    }
    #pragma unroll
    for (int k = 0; k < DIM / 4; ++k) {
        float4 t = ((const float4*)fxb)[k];
        fb[4*k+0] = t.x; fb[4*k+1] = t.y; fb[4*k+2] = t.z; fb[4*k+3] = t.w;
    }

    // Pin fa/fb in VGPRs (identity asm: values defined by asm can't be
    // rematerialized from memory). waves_per_eu(2,8) -> 256-VGPR budget,
    // ~160 used, no spill.
    #define PIN16(a, b) asm volatile("" \
        : "+v"(a[(b)+0]),  "+v"(a[(b)+1]),  "+v"(a[(b)+2]),  "+v"(a[(b)+3]), \
          "+v"(a[(b)+4]),  "+v"(a[(b)+5]),  "+v"(a[(b)+6]),  "+v"(a[(b)+7]), \
          "+v"(a[(b)+8]),  "+v"(a[(b)+9]),  "+v"(a[(b)+10]), "+v"(a[(b)+11]), \
          "+v"(a[(b)+12]), "+v"(a[(b)+13]), "+v"(a[(b)+14]), "+v"(a[(b)+15]))
    PIN16(fa, 0); PIN16(fa, 16); PIN16(fa, 32); PIN16(fa, 48);
    PIN16(fb, 0); PIN16(fb, 16); PIN16(fb, 32); PIN16(fb, 48);
    #undef PIN16

    // A per vector: numpy pairwise, n=64 -> 8 accumulators stride 8, then
    // ((r0+r1)+(r2+r3))+((r4+r5)+(r6+r7)). Plain mul+add (contract off).
    float ra[8], rb[8];
    #pragma unroll
    for (int k = 0; k < 8; ++k) { ra[k] = fa[k] * fa[k]; rb[k] = fb[k] * fb[k]; }
    #pragma unroll
    for (int b = 1; b < 8; ++b) {
        #pragma unroll
        for (int k = 0; k < 8; ++k) {
            float t0 = fa[8*b + k] * fa[8*b + k];
            ra[k] = ra[k] + t0;
            float t1 = fb[8*b + k] * fb[8*b + k];
            rb[k] = rb[k] + t1;
        }
    }
    float Aa = ((ra[0] + ra[1]) + (ra[2] + ra[3])) + ((ra[4] + ra[5]) + (ra[6] + ra[7]));
    float Ab = ((rb[0] + rb[1]) + (rb[2] + rb[3])) + ((rb[4] + rb[5]) + (rb[6] + rb[7]));

    // wave-uniform code segment -> addresses uniform -> compiler emits
    // s_load (SGPR e-stream; one scalar float feeds 2 FMAs). Proven in R1.
    const float* eseg = ET + (size_t)wq * 256 * DIM;
    const float* Cseg = C + wq * 256;
    float bda = 3.0e38f, bdb = 3.0e38f;
    int   bia = wq * 256, bib = wq * 256;
    #pragma unroll 2
    for (int jj = 0; jj < 256; ++jj) {
        const float* e = eseg + jj * DIM;
        float ma = 0.0f, mb = 0.0f;
        #pragma unroll
        for (int d = 0; d < DIM; ++d) {
            float ev = e[d];
            ma = __builtin_fmaf(fa[d], ev, ma);
            mb = __builtin_fmaf(fb[d], ev, mb);
        }
        int j = wq * 256 + jj;
        float Cv = Cseg[jj];
        float t1a = 2.0f * ma;           // exact (x2)
        float t2a = Aa - t1a;            // rounded
        float da  = t2a + Cv;            // rounded
        float t1b = 2.0f * mb;
        float t2b = Ab - t1b;
        float db  = t2b + Cv;
        if (da < bda) { bda = da; bia = j; }
        if (db < bdb) { bdb = db; bib = j; }
    }

    sda[wq][lane] = bda; sia[wq][lane] = bia;
    sdb[wq][lane] = bdb; sib[wq][lane] = bib;
    __syncthreads();

    if (wq == 0) {
        // 2-way merge, tie -> smaller index (wave0 has lower j): numpy
        // first-min. Same comparator as the proven 4-way merge.
        float bd = sda[0][lane]; int bi = sia[0][lane];
        {
            float d2 = sda[1][lane]; int i2 = sia[1][lane];
            if (d2 < bd || (d2 == bd && i2 < bi)) { bd = d2; bi = i2; }
        }
        sba[lane] = bi;
        out[IND_OFF + va] = (float)bi;   // coalesced
        indI[va] = bi;

        bd = sdb[0][lane]; bi = sib[0][lane];
        {
            float d2 = sdb[1][lane]; int i2 = sib[1][lane];
            if (d2 < bd || (d2 == bd && i2 < bi)) { bd = d2; bi = i2; }
        }
        sbb[lane] = bi;
        out[IND_OFF + vb] = (float)bi;
        indI[vb] = bi;
    }
    __syncthreads();

    // epilogue: wave0 -> va rows (vs fa), wave1 -> vb rows (vs fb).
    int bsel = (wq == 0) ? sba[lane] : sbb[lane];
    int vsel = (wq == 0) ? va : vb;
    const float4* qr = (const float4*)(ET + (size_t)bsel * DIM);
    float4* orow = (float4*)(out + Q_OFF + (size_t)vsel * DIM);
    float dl = 0.0f;
    if (wq == 0) {
        #pragma unroll
        for (int k = 0; k < 16; ++k) {
            float4 tq = qr[k];
            float r0 = tq.x - fa[4*k+0];
            float r1 = tq.y - fa[4*k+1];
            float r2 = tq.z - fa[4*k+2];
            float r3 = tq.w - fa[4*k+3];
            dl = __builtin_fmaf(r0, r0, dl); dl = __builtin_fmaf(r1, r1, dl);
            dl = __builtin_fmaf(r2, r2, dl); dl = __builtin_fmaf(r3, r3, dl);
            orow[k] = tq;
        }
    } else {
        #pragma unroll
        for (int k = 0; k < 16; ++k) {
            float4 tq = qr[k];
            float r0 = tq.x - fb[4*k+0];
            float r1 = tq.y - fb[4*k+1];
            float r2 = tq.z - fb[4*k+2];
            float r3 = tq.w - fb[4*k+3];
            dl = __builtin_fmaf(r0, r0, dl); dl = __builtin_fmaf(r1, r1, dl);
            dl = __builtin_fmaf(r2, r2, dl); dl = __builtin_fmaf(r3, r3, dl);
            orow[k] = tq;
        }
    }

    #pragma unroll
    for (int off = 32; off > 0; off >>= 1) dl += __shfl_down(dl, off);
    if (lane == 0) wdl[wq] = dl;
    __syncthreads();
    if (threadIdx.x == 0) dpart[blockIdx.x] = wdl[0] + wdl[1];
}

// ============ stats: 4 blocks x 8 waves per code, int4 ballot scan =======
__global__ __launch_bounds__(512) void vq_stats(
    const float* __restrict__ x,
    const int* __restrict__ indI,      // ws + INDI_OFF
    float* __restrict__ pcnt,          // ws + PCNT_OFF   [4][K]
    float* __restrict__ pesum)         // ws + PESUM_OFF  [4][K][DIM]
{
    __shared__ float p[8][DIM];
    __shared__ float c[8];
    int j    = blockIdx.x >> 2;
    int q    = blockIdx.x & 3;
    int lane = threadIdx.x & 63;
    int w    = __builtin_amdgcn_readfirstlane(threadIdx.x >> 6);

    int seg  = q * 8 + w;              // 0..31
    int base = seg * (NVEC / 32);      // 4096 ids per segment

    float acc = 0.0f;
    int   cnt = 0;
    for (int i = 0; i < NVEC / 32; i += 256) {
        int4 idv = ((const int4*)(indI + base + i))[lane];  // 256 ids/wave
        unsigned long long m0 = __ballot(idv.x == j);
        unsigned long long m1 = __ballot(idv.y == j);
        unsigned long long m2 = __ballot(idv.z == j);
        unsigned long long m3 = __ballot(idv.w == j);
        cnt += (int)(__popcll(m0) + __popcll(m1) + __popcll(m2) + __popcll(m3));
        while (m0) { int b = __builtin_ctzll(m0); m0 &= m0 - 1;
                     acc += x[(size_t)(base + i + 4*b + 0) * DIM + lane]; }
        while (m1) { int b = __builtin_ctzll(m1); m1 &= m1 - 1;
                     acc += x[(size_t)(base + i + 4*b + 1) * DIM + lane]; }
        while (m2) { int b = __builtin_ctzll(m2); m2 &= m2 - 1;
                     acc += x[(size_t)(base + i + 4*b + 2) * DIM + lane]; }
        while (m3) { int b = __builtin_ctzll(m3); m3 &= m3 - 1;
                     acc += x[(size_t)(base + i + 4*b + 3) * DIM + lane]; }
    }
    p[w][lane] = acc;
    if (lane == 0) c[w] = (float)cnt;
    __syncthreads();
    if (w == 0) {
        float s = ((p[0][lane] + p[1][lane]) + (p[2][lane] + p[3][lane]))
                + ((p[4][lane] + p[5][lane]) + (p[6][lane] + p[7][lane]));
        pesum[((size_t)q * K + j) * DIM + lane] = s;
        if (lane == 0)
            pcnt[q * K + j] = ((c[0] + c[1]) + (c[2] + c[3]))
                            + ((c[4] + c[5]) + (c[6] + c[7]));
    }
}

// ============ finalize stage 1: scalars (ncs, n, diff) — 1 block =========
__global__ __launch_bounds__(512) void vq_finalize1(
    const float* __restrict__ cluster_size,
    float* __restrict__ ws,
    float* __restrict__ out)
{
    __shared__ float wsum[8];
    __shared__ float dsum_sh[8];
    int j = threadIdx.x;  // 512 threads, one per code

    float cj = ((ws[PCNT_OFF + 0*K + j] + ws[PCNT_OFF + 1*K + j])
              + (ws[PCNT_OFF + 2*K + j] + ws[PCNT_OFF + 3*K + j]));
    float ncs = DECAYF * cluster_size[j] + OMDF * cj;
    out[NCS_OFF + j] = ncs;

    // diff: sum 1024 block partials (deterministic)
    float dsum = 0.0f;
    #pragma unroll
    for (int k = 0; k < NBLK_ASSIGN / 512; ++k)
        dsum += ws[DPART_OFF + k * 512 + j];

    float s = ncs;
    #pragma unroll
    for (int off = 32; off > 0; off >>= 1) {
        s    += __shfl_down(s, off);
        dsum += __shfl_down(dsum, off);
    }
    if ((j & 63) == 0) { wsum[j >> 6] = s; dsum_sh[j >> 6] = dsum; }
    __syncthreads();
    if (j == 0) {
        float n = 0.f, dtot = 0.f;
        #pragma unroll
        for (int w = 0; w < 8; ++w) { n += wsum[w]; dtot += dsum_sh[w]; }
        ws[NSH_OFF] = n;
        out[DIFF_OFF] = dtot * (1.0f / 8388608.0f);  // 2^23: exact
    }
}

// ============ finalize stage 2: embed EMA + normalize — 64 blocks ========
__global__ __launch_bounds__(512) void vq_finalize2(
    const float* __restrict__ embed_avg,
    const float* __restrict__ ws,
    float* __restrict__ out)
{
    int d = blockIdx.x;     // 0..63
    int j = threadIdx.x;    // 0..511

    float ncs = out[NCS_OFF + j];
    float n   = ws[NSH_OFF];
    float csz = (ncs + EPSF) / (n + (float)K * EPSF) * n;

    float es = ((ws[PESUM_OFF + ((size_t)0*K + j) * DIM + d]
               + ws[PESUM_OFF + ((size_t)1*K + j) * DIM + d])
              + (ws[PESUM_OFF + ((size_t)2*K + j) * DIM + d]
               + ws[PESUM_OFF + ((size_t)3*K + j) * DIM + d]));
    float ea = DECAYF * embed_avg[d * K + j] + OMDF * es;
    out[NEA_OFF + d * K + j] = ea;        // coalesced over j
    out[NE_OFF  + d * K + j] = ea / csz;
}

// ============ launch ============
extern "C" void kernel_launch(void* const* d_in, const int* in_sizes, int n_in,
                              void* d_out, int out_size, void* d_ws, size_t ws_size,
                              hipStream_t stream) {
    const float* x            = (const float*)d_in[0];
    const float* embed        = (const float*)d_in[1];
    const float* cluster_size = (const float*)d_in[2];
    const float* embed_avg    = (const float*)d_in[3];
    float* out = (float*)d_out;
    float* ws  = (float*)d_ws;
    int*   indI = (int*)(ws + INDI_OFF);

    vq_prep<<<K / 256, 256, 0, stream>>>(embed, ws);
    vq_assign<<<NBLK_ASSIGN, 128, 0, stream>>>(
        x, ws + ET_OFF, ws + C_OFF, indI, ws + DPART_OFF, out);
    vq_stats<<<K * 4, 512, 0, stream>>>(
        x, indI, ws + PCNT_OFF, ws + PESUM_OFF);
    vq_finalize1<<<1, K, 0, stream>>>(cluster_size, ws, out);
    vq_finalize2<<<DIM, K, 0, stream>>>(embed_avg, ws, out);
}